// Round 8
// baseline (175.045 us; speedup 1.0000x reference)
//
#include <hip/hip_runtime.h>
#include <stdint.h>

// ComplexWaveformSystem: sim[b,t] = |rx[b,:] . conj(ifft_ortho(freq[t,:]))|^2 / temp
// B = 8192, T = 8192, L = 128, K = 2L = 256 (re/im interleaved bf16)
//
// r8 design: wave-private GEMM, no LDS, no barriers, no manual waitcnt.
//  - wave owns 32(M)x32(N); B-panel (32 tokens x K) lives in 64 VGPRs, loaded once
//  - A-frags stream global->reg via 4-deep static prefetch ring (wave-exclusive rows)
//  - grid 2048 = 8 M-groups (bid%8 -> XCD: 512KB A-slice L2-hot) x 256 N-blocks

#define T_TOKENS 8192
#define B_BATCH  8192
#define L_SEQ    128

typedef __bf16 bf16x8 __attribute__((ext_vector_type(8)));
typedef float  f32x4  __attribute__((ext_vector_type(4)));
typedef unsigned int u32x4 __attribute__((ext_vector_type(4)));

__device__ __forceinline__ unsigned short f2bf(float f) {
  unsigned int u = __builtin_bit_cast(unsigned int, f);
  u += 0x7FFFu + ((u >> 16) & 1u);
  return (unsigned short)(u >> 16);
}

// ---------------- prep 1: bank = ifft_ortho(freq); interleaved bf16 (re,im) per u32
__global__ void build_bank_kernel(const float* __restrict__ fr,
                                  const float* __restrict__ fi,
                                  unsigned int* __restrict__ B2) {
  __shared__ float  sfr[L_SEQ], sfi[L_SEQ];
  __shared__ float2 stw[L_SEQ];
  const int t = blockIdx.x, l = threadIdx.x;
  sfr[l] = fr[t * L_SEQ + l];
  sfi[l] = fi[t * L_SEQ + l];
  float sn, cs;
  __sincosf(6.283185307179586f * (float)l * (1.0f / 128.0f), &sn, &cs);
  stw[l] = make_float2(cs, sn);
  __syncthreads();
  float br = 0.f, bi = 0.f;
#pragma unroll 8
  for (int k = 0; k < L_SEQ; ++k) {
    const float2 tw = stw[(k * l) & 127];
    const float xr = sfr[k], xi = sfi[k];
    br = fmaf(xr, tw.x, br); br = fmaf(-xi, tw.y, br);
    bi = fmaf(xr, tw.y, bi); bi = fmaf(xi, tw.x, bi);
  }
  const float sc = 0.08838834764831845f;  // 1/sqrt(128)
  const unsigned int lo = f2bf(br * sc);
  const unsigned int hi = f2bf(bi * sc);
  B2[t * L_SEQ + l] = lo | (hi << 16);
}

// ---------------- prep 2: A2[b][2l] = rx_r, A2[b][2l+1] = rx_i
__global__ void build_a_kernel(const float* __restrict__ rr,
                               const float* __restrict__ ri,
                               unsigned int* __restrict__ A2) {
  const int i = blockIdx.x * 256 + threadIdx.x;
  const unsigned int lo = f2bf(rr[i]);
  const unsigned int hi = f2bf(ri[i]);
  A2[i] = lo | (hi << 16);
}

// imag A-fragment: per u32 word (re,im) -> (im,-re)   [verified r1]
__device__ __forceinline__ bf16x8 make_imag(bf16x8 a) {
  u32x4 u = __builtin_bit_cast(u32x4, a);
#pragma unroll
  for (int i = 0; i < 4; ++i)
    u[i] = ((u[i] >> 16) | (u[i] << 16)) ^ 0x80000000u;
  return __builtin_bit_cast(bf16x8, u);
}

__global__ __launch_bounds__(256, 3) void gemm_kernel(
    const char* __restrict__ A2, const char* __restrict__ B2,
    const float* __restrict__ temp, float* __restrict__ out) {
  const int tid  = threadIdx.x;
  const int lane = tid & 63;
  const int wid  = tid >> 6;
  const float inv_t = 1.0f / temp[0];

  const int bid  = blockIdx.x;
  const int g    = bid & 7;    // M-group (rides HW round-robin -> one XCD per group)
  const int nblk = bid >> 3;   // token block, 32 tokens

  const int lrow = lane & 15;
  const int lk16 = (lane >> 4) * 16;   // 16B k-offset within 64B chunk

  // ---- B panel to registers: br[kc][n], 16 x b128 (one-time, L2-served)
  bf16x8 br[8][2];
  {
    const char* bb = B2 + (size_t)(nblk * 32 + lrow) * 512 + lk16;
#pragma unroll
    for (int kc = 0; kc < 8; ++kc) {
#pragma unroll
      for (int n = 0; n < 2; ++n)
        br[kc][n] = *(const bf16x8*)(bb + (size_t)n * 16 * 512 + kc * 64);
    }
  }

  // ---- A addressing: wave-exclusive 32 rows per M-tile
  const size_t aoff0 = (size_t)lrow * 512 + lk16;   // frag m=0 (rows +0..15)
  const size_t aoff1 = aoff0 + 16 * 512;            // frag m=1 (rows +16..31)
  const char* pA = A2 + ((size_t)g * 1024 + wid * 32) * 512;

  f32x4 accre[2][2], accim[2][2];
#pragma unroll
  for (int m = 0; m < 2; ++m)
#pragma unroll
    for (int n = 0; n < 2; ++n) {
      accre[m][n] = f32x4{0.f, 0.f, 0.f, 0.f};
      accim[m][n] = f32x4{0.f, 0.f, 0.f, 0.f};
    }

  // ---- 4-deep A prefetch ring (static indices only)
  bf16x8 ar[4][2];
#pragma unroll
  for (int kc = 0; kc < 4; ++kc) {
    ar[kc][0] = *(const bf16x8*)(pA + aoff0 + kc * 64);
    ar[kc][1] = *(const bf16x8*)(pA + aoff1 + kc * 64);
  }

  for (int t = 0; t < 8; ++t) {
    const char* pcur  = pA + (size_t)t * 128 * 512;
    const char* pnext = (t == 7) ? pcur : pcur + 128 * 512;  // clamp: dead loads, in-bounds

#define PH(KC, PS, KS) do {                                                  \
    const bf16x8 a0 = ar[(KC) & 3][0], a1 = ar[(KC) & 3][1];                 \
    ar[(KC) & 3][0] = *(const bf16x8*)((PS) + aoff0 + (KS) * 64);            \
    ar[(KC) & 3][1] = *(const bf16x8*)((PS) + aoff1 + (KS) * 64);            \
    const bf16x8 ai0 = make_imag(a0), ai1 = make_imag(a1);                   \
    accre[0][0] = __builtin_amdgcn_mfma_f32_16x16x32_bf16(a0, br[KC][0], accre[0][0], 0, 0, 0); \
    accim[0][0] = __builtin_amdgcn_mfma_f32_16x16x32_bf16(ai0, br[KC][0], accim[0][0], 0, 0, 0); \
    accre[0][1] = __builtin_amdgcn_mfma_f32_16x16x32_bf16(a0, br[KC][1], accre[0][1], 0, 0, 0); \
    accim[0][1] = __builtin_amdgcn_mfma_f32_16x16x32_bf16(ai0, br[KC][1], accim[0][1], 0, 0, 0); \
    accre[1][0] = __builtin_amdgcn_mfma_f32_16x16x32_bf16(a1, br[KC][0], accre[1][0], 0, 0, 0); \
    accim[1][0] = __builtin_amdgcn_mfma_f32_16x16x32_bf16(ai1, br[KC][0], accim[1][0], 0, 0, 0); \
    accre[1][1] = __builtin_amdgcn_mfma_f32_16x16x32_bf16(a1, br[KC][1], accre[1][1], 0, 0, 0); \
    accim[1][1] = __builtin_amdgcn_mfma_f32_16x16x32_bf16(ai1, br[KC][1], accim[1][1], 0, 0, 0); \
  } while (0)

    PH(0, pcur, 4);  PH(1, pcur, 5);  PH(2, pcur, 6);  PH(3, pcur, 7);
    PH(4, pnext, 0); PH(5, pnext, 1); PH(6, pnext, 2); PH(7, pnext, 3);
#undef PH

    // epilogue: sim = (re^2+im^2)*inv_t ; C layout col=lane&15, row=(lane>>4)*4+reg
    const int r0 = g * 1024 + t * 128 + wid * 32 + ((lane >> 4) << 2);
    const int c0 = nblk * 32 + lrow;
#pragma unroll
    for (int m = 0; m < 2; ++m) {
#pragma unroll
      for (int n = 0; n < 2; ++n) {
        const f32x4 re = accre[m][n];
        const f32x4 im = accim[m][n];
#pragma unroll
        for (int j = 0; j < 4; ++j) {
          __builtin_nontemporal_store(
              (re[j] * re[j] + im[j] * im[j]) * inv_t,
              &out[(size_t)(r0 + m * 16 + j) * T_TOKENS + (c0 + n * 16)]);
        }
        accre[m][n] = f32x4{0.f, 0.f, 0.f, 0.f};
        accim[m][n] = f32x4{0.f, 0.f, 0.f, 0.f};
      }
    }
  }
}

extern "C" void kernel_launch(void* const* d_in, const int* in_sizes, int n_in,
                              void* d_out, int out_size, void* d_ws, size_t ws_size,
                              hipStream_t stream) {
  const float* rx_r = (const float*)d_in[0];
  const float* rx_i = (const float*)d_in[1];
  const float* fq_r = (const float*)d_in[2];
  const float* fq_i = (const float*)d_in[3];
  const float* temp = (const float*)d_in[4];
  float* out = (float*)d_out;

  unsigned int* B2 = (unsigned int*)d_ws;                          // 4 MB bank
  unsigned int* A2 = (unsigned int*)((char*)d_ws + (4u << 20));    // 4 MB rx

  build_bank_kernel<<<T_TOKENS, L_SEQ, 0, stream>>>(fq_r, fq_i, B2);
  build_a_kernel<<<(B_BATCH * L_SEQ) / 256, 256, 0, stream>>>(rx_r, rx_i, A2);
  gemm_kernel<<<8 * (T_TOKENS / 32), 256, 0, stream>>>(
      (const char*)A2, (const char*)B2, temp, out);
}

// Round 9
// 144.697 us; speedup vs baseline: 1.2097x; 1.2097x over previous
//
#include <hip/hip_runtime.h>
#include <stdint.h>

// ComplexWaveformSystem: sim[b,t] = |rx[b,:] . conj(ifft_ortho(freq[t,:]))|^2 / temp
// B = 8192, T = 8192, L = 128, K = 2L = 256 (re/im interleaved bf16)
//
// r9: r5/r6-proven 8-phase counted-vmcnt ring, shrunk to BM=64 x BN=64 so
// 4-5 blocks fit per CU (32 KB LDS) -> ~2x resident waves vs r6. All sync
// structure identical (two-lane discipline: geometry-only change).

#define T_TOKENS 8192
#define B_BATCH  8192
#define L_SEQ    128

#define SLOT_BYTES 8192    // A region 4 KB + B region 4 KB
#define SB_OFF     4096

typedef __bf16 bf16x8 __attribute__((ext_vector_type(8)));
typedef float  f32x4  __attribute__((ext_vector_type(4)));
typedef unsigned int u32x4 __attribute__((ext_vector_type(4)));

__device__ __forceinline__ unsigned short f2bf(float f) {
  unsigned int u = __builtin_bit_cast(unsigned int, f);
  u += 0x7FFFu + ((u >> 16) & 1u);
  return (unsigned short)(u >> 16);
}

// ---------------- prep 1: bank = ifft_ortho(freq); interleaved bf16 (re,im) per u32
__global__ void build_bank_kernel(const float* __restrict__ fr,
                                  const float* __restrict__ fi,
                                  unsigned int* __restrict__ B2) {
  __shared__ float  sfr[L_SEQ], sfi[L_SEQ];
  __shared__ float2 stw[L_SEQ];
  const int t = blockIdx.x, l = threadIdx.x;
  sfr[l] = fr[t * L_SEQ + l];
  sfi[l] = fi[t * L_SEQ + l];
  float sn, cs;
  __sincosf(6.283185307179586f * (float)l * (1.0f / 128.0f), &sn, &cs);
  stw[l] = make_float2(cs, sn);
  __syncthreads();
  float br = 0.f, bi = 0.f;
#pragma unroll 8
  for (int k = 0; k < L_SEQ; ++k) {
    const float2 tw = stw[(k * l) & 127];
    const float xr = sfr[k], xi = sfi[k];
    br = fmaf(xr, tw.x, br); br = fmaf(-xi, tw.y, br);
    bi = fmaf(xr, tw.y, bi); bi = fmaf(xi, tw.x, bi);
  }
  const float sc = 0.08838834764831845f;  // 1/sqrt(128)
  const unsigned int lo = f2bf(br * sc);
  const unsigned int hi = f2bf(bi * sc);
  B2[t * L_SEQ + l] = lo | (hi << 16);
}

// ---------------- prep 2: A2[b][2l] = rx_r, A2[b][2l+1] = rx_i
__global__ void build_a_kernel(const float* __restrict__ rr,
                               const float* __restrict__ ri,
                               unsigned int* __restrict__ A2) {
  const int i = blockIdx.x * 256 + threadIdx.x;
  const unsigned int lo = f2bf(rr[i]);
  const unsigned int hi = f2bf(ri[i]);
  A2[i] = lo | (hi << 16);
}

// ---------------- GEMM
// NOTE: NEVER pass a nonzero `offset` to global_load_lds (r4->r5 NaN fix) —
// chunk advance goes through the laundered global pointer, offset stays 0.
__device__ __forceinline__ void gl_lds16(const char* g, char* l) {
  __builtin_amdgcn_global_load_lds(
      (const __attribute__((address_space(1))) unsigned int*)g,
      (__attribute__((address_space(3))) unsigned int*)l, 16, 0, 0);
}

// imag A-fragment: per u32 word (re,im) -> (im,-re)   [verified r1]
__device__ __forceinline__ bf16x8 make_imag(bf16x8 a) {
  u32x4 u = __builtin_bit_cast(u32x4, a);
#pragma unroll
  for (int i = 0; i < 4; ++i)
    u[i] = ((u[i] >> 16) | (u[i] << 16)) ^ 0x80000000u;
  return __builtin_bit_cast(bf16x8, u);
}

// bank-conflict swizzle: XOR byte bits [5:4] with s(row) = (row + row>>2) & 3
__device__ __forceinline__ int swz4(int row) { return ((row + (row >> 2)) & 3) << 4; }

extern __shared__ __align__(16) char smem[];   // 4 slots x 8 KB = 32 KB

__global__ __launch_bounds__(256, 4) void gemm_kernel(
    const char* __restrict__ A2, const char* __restrict__ B2,
    const float* __restrict__ temp, float* __restrict__ out) {
  const int tid  = threadIdx.x;
  const int lane = tid & 63;
  const int wid  = tid >> 6;

  // pin the temperature load BEFORE any staging so the vmcnt queue starts empty
  const float inv_t = 1.0f / temp[0];
  asm volatile("" :: "v"(inv_t));

  // XCD-bijective block swizzle: 16384 blocks, 2048 contiguous per XCD
  const int bid  = blockIdx.x;
  const int swz  = (bid & 7) * 2048 + (bid >> 3);
  const int brow = swz >> 7;    // 0..127  (batch / 64)
  const int bcol = swz & 127;   // 0..127  (tokens / 64)
  const int wr = wid >> 1, wc = wid & 1;   // 2M x 2N waves, 32x32 each

  // per-lane pre-swizzled global source pointers (chunk 0; chunk k adds k*64)
  const int lr = lane >> 2, lm = lane & 3;
  const int rowA = wid * 16 + lr;           // A rows 0..63
  const int rowB = wid * 16 + lr;           // B rows 0..63
  const char* gA = A2 + (size_t)(brow * 64 + rowA) * 512 + ((lm * 16) ^ swz4(rowA));
  const char* gB = B2 + (size_t)(bcol * 64 + rowB) * 512 + ((lm * 16) ^ swz4(rowB));

  // ds_read fragment offsets (region-relative, swizzled)
  int offA[2], offB[2];
  const int cb = (lane >> 4) * 16;
#pragma unroll
  for (int m = 0; m < 2; ++m) {
    const int r = wr * 32 + m * 16 + (lane & 15);
    offA[m] = r * 64 + (cb ^ swz4(r));
  }
#pragma unroll
  for (int n = 0; n < 2; ++n) {
    const int r = wc * 32 + n * 16 + (lane & 15);
    offB[n] = SB_OFF + r * 64 + (cb ^ swz4(r));
  }

  f32x4 accre[2][2], accim[2][2];
#pragma unroll
  for (int m = 0; m < 2; ++m)
#pragma unroll
    for (int n = 0; n < 2; ++n) {
      accre[m][n] = f32x4{0.f, 0.f, 0.f, 0.f};
      accim[m][n] = f32x4{0.f, 0.f, 0.f, 0.f};
    }

  // chunk offset laundered through an opaque VGPR (keeps offset: immediate 0)
#define STAGE(KC) do {                                                     \
    char* sl_ = smem + ((KC) & 3) * SLOT_BYTES;                            \
    int koff_ = (KC) * 64;                                                 \
    asm("" : "+v"(koff_));                                                 \
    gl_lds16(gA + koff_, sl_ + wid * 1024);                                \
    gl_lds16(gB + koff_, sl_ + SB_OFF + wid * 1024);                       \
  } while (0)

#define FENCE asm volatile("" ::: "memory")

// phase C: ds_read chunk C (slot C&3); stage chunk C+3; counted vmcnt retires
// chunk C+1 (2 loads per STAGE: steady outstanding 6 -> vmcnt(4)).
// lgkmcnt(0) after barrier #1 pins ds_read completion before barrier #2
// (WAR guard vs next phase's STAGE overwriting the oldest slot).
#define PHASE(C, VM, DOSTAGE) do {                                         \
    const char* slb_ = smem + ((C) & 3) * SLOT_BYTES;                      \
    bf16x8 a_[2], b_[2];                                                   \
    _Pragma("unroll") for (int m = 0; m < 2; ++m)                          \
      a_[m] = *(const bf16x8*)(slb_ + offA[m]);                            \
    _Pragma("unroll") for (int n = 0; n < 2; ++n)                          \
      b_[n] = *(const bf16x8*)(slb_ + offB[n]);                            \
    if (DOSTAGE) { STAGE((C) + 3); }                                       \
    if ((VM) == 4)      asm volatile("s_waitcnt vmcnt(4)" ::: "memory");   \
    else if ((VM) == 2) asm volatile("s_waitcnt vmcnt(2)" ::: "memory");   \
    else if ((VM) == 0) asm volatile("s_waitcnt vmcnt(0)" ::: "memory");   \
    __builtin_amdgcn_s_barrier();                                          \
    asm volatile("s_waitcnt lgkmcnt(0)" ::: "memory");                     \
    __builtin_amdgcn_s_setprio(1);                                         \
    _Pragma("unroll") for (int m = 0; m < 2; ++m) {                        \
      const bf16x8 ai_ = make_imag(a_[m]);                                 \
      _Pragma("unroll") for (int n = 0; n < 2; ++n) {                      \
        accre[m][n] = __builtin_amdgcn_mfma_f32_16x16x32_bf16(             \
            a_[m], b_[n], accre[m][n], 0, 0, 0);                           \
        accim[m][n] = __builtin_amdgcn_mfma_f32_16x16x32_bf16(             \
            ai_, b_[n], accim[m][n], 0, 0, 0);                             \
      }                                                                    \
    }                                                                      \
    __builtin_amdgcn_s_setprio(0);                                         \
    __builtin_amdgcn_s_barrier();                                          \
    FENCE;                                                                 \
  } while (0)

  // queue provably empty before staging begins
  asm volatile("s_waitcnt vmcnt(0) lgkmcnt(0)" ::: "memory");

  // prologue: stage chunks 0,1,2 (6 loads); retire chunk 0
  STAGE(0); STAGE(1); STAGE(2);
  asm volatile("s_waitcnt vmcnt(4)" ::: "memory");
  __builtin_amdgcn_s_barrier();
  FENCE;

  PHASE(0, 4, 1);
  PHASE(1, 4, 1);
  PHASE(2, 4, 1);
  PHASE(3, 4, 1);
  PHASE(4, 4, 1);
  PHASE(5, 2, 0);
  PHASE(6, 0, 0);
  PHASE(7, -1, 0);

#undef PHASE
#undef STAGE

  // epilogue: sim = (re^2 + im^2) * inv_t ; C layout col=lane&15, row=(lane>>4)*4+reg
  // nontemporal: keeps L2 for A2/B2 panels (r8 evidence: FETCH 85->21 MB)
  const int r0 = brow * 64 + wr * 32 + ((lane >> 4) << 2);
  const int c0 = bcol * 64 + wc * 32 + (lane & 15);
#pragma unroll
  for (int m = 0; m < 2; ++m) {
#pragma unroll
    for (int n = 0; n < 2; ++n) {
      const f32x4 re = accre[m][n];
      const f32x4 im = accim[m][n];
#pragma unroll
      for (int j = 0; j < 4; ++j) {
        __builtin_nontemporal_store(
            (re[j] * re[j] + im[j] * im[j]) * inv_t,
            &out[(size_t)(r0 + m * 16 + j) * T_TOKENS + (c0 + n * 16)]);
      }
    }
  }
}

extern "C" void kernel_launch(void* const* d_in, const int* in_sizes, int n_in,
                              void* d_out, int out_size, void* d_ws, size_t ws_size,
                              hipStream_t stream) {
  const float* rx_r = (const float*)d_in[0];
  const float* rx_i = (const float*)d_in[1];
  const float* fq_r = (const float*)d_in[2];
  const float* fq_i = (const float*)d_in[3];
  const float* temp = (const float*)d_in[4];
  float* out = (float*)d_out;

  unsigned int* B2 = (unsigned int*)d_ws;                          // 4 MB bank
  unsigned int* A2 = (unsigned int*)((char*)d_ws + (4u << 20));    // 4 MB rx

  (void)hipFuncSetAttribute((const void*)gemm_kernel,
                            hipFuncAttributeMaxDynamicSharedMemorySize, 32768);

  build_bank_kernel<<<T_TOKENS, L_SEQ, 0, stream>>>(fq_r, fq_i, B2);
  build_a_kernel<<<(B_BATCH * L_SEQ) / 256, 256, 0, stream>>>(rx_r, rx_i, A2);
  gemm_kernel<<<(B_BATCH / 64) * (T_TOKENS / 64), 256, 32768, stream>>>(
      (const char*)A2, (const char*)B2, temp, out);
}